// Round 12
// baseline (609.799 us; speedup 1.0000x reference)
//
#include <hip/hip_runtime.h>
#include <hip/hip_bf16.h>

// NRDE layer. Structure:
//   A[a][b][.] = coeff[b,a,:] @ btt^T   (bf16 MFMA GEMM, fp32 accum, stored f16)
//     A column order is permuted: c' = (w>>3)*1024 + h*8 + (w&7), so the scan's
//     A-matvec reads contiguous 128B granules per 8-lane group.
//   GEMM operands pre-stored K-BLOCKED: [kk*4+q][row][8 bf16] -> lane-linear
//   staging, conflict-free ds_read_b128 fragments, zero padding.
//   agemm: R6 form (best measured): grid (cc,256), 512 thr / 8 waves, wave tile
//     32x64, full K staged once, ONE barrier, 320 MFMAs/block, 80KB LDS.
//   scan: 1 block of 512 thr (8 waves) per batch element, weights register/L2-
//     resident (compiler picks ~124 VGPR), SMALL LDS (4.6KB) so 2 blocks/CU
//     co-reside (R11's 96KB pad forced 1 block/CU while the compiler never took
//     the 256-VGPR budget -- pad removed, TLP doubled).
//     A-slice for k2 (index n) is REUSED as next step's k1 slice (a1(n+1)=n).

#define BB 128
#define SS 64
#define LL 137
#define HH 128
#define DIN 64
#define WW 256
#define DD 136          // L-1
#define KP 160          // GEMM K padded to 5*32
#define NC 32768        // H*W
#define OUT2_OFF ((size_t)BB*(SS+1)*HH)

typedef __hip_bfloat16 bf16;
typedef __attribute__((ext_vector_type(8))) short short8;
typedef __attribute__((ext_vector_type(4))) float f32x4;
typedef _Float16 h2t __attribute__((ext_vector_type(2)));

__device__ __forceinline__ bf16 f2bf(float x){ return __float2bfloat16(x); }

__device__ __forceinline__ float fdot2u(unsigned w, unsigned y, float acc){
#if __has_builtin(__builtin_amdgcn_fdot2)
  return __builtin_amdgcn_fdot2(__builtin_bit_cast(h2t, w),
                                __builtin_bit_cast(h2t, y), acc, false);
#else
  h2t a = __builtin_bit_cast(h2t, w), b2 = __builtin_bit_cast(h2t, y);
  return acc + (float)a[0]*(float)b2[0] + (float)a[1]*(float)b2[1];
#endif
}
__device__ __forceinline__ float dot8(uint4 w, uint4 y, float acc){
  acc = fdot2u(w.x, y.x, acc);
  acc = fdot2u(w.y, y.y, acc);
  acc = fdot2u(w.z, y.z, acc);
  acc = fdot2u(w.w, y.w, acc);
  return acc;
}

__device__ __forceinline__ float fast_tanh(float x){
  float e = __expf(2.f*x);
#if __has_builtin(__builtin_amdgcn_rcpf)
  float r = __builtin_amdgcn_rcpf(e + 1.f);
#else
  float r = 1.f/(e + 1.f);
#endif
  return 1.f - 2.f*r;
}

// ---------------- prep: coeff rows m=a*128+b (fp32 -> bf16), K-BLOCKED ----------------
__global__ void prep_coeff(const float* __restrict__ logsig, bf16* __restrict__ cA){
  int m = blockIdx.x;            // 0..8191
  int d = threadIdx.x;           // 0..159
  int a = m >> 7, b = m & 127;
  float v = 0.0f;
  if (d < DD) v = logsig[(size_t)(b*SS + a)*LL + 1 + d];
  int kk = d >> 5, q = (d >> 3) & 3, jj = d & 7;
  cA[(((size_t)(kk*4 + q))*8192 + m)*8 + jj] = f2bf(v);
}

// ---------------- prep: btt rows in PERMUTED col order c', K-BLOCKED ----------------
// c' = wc*1024 + h*8 + wlow -> w = ((c'>>10)<<3)|(c'&7), h = (c'>>3)&127
__global__ void prep_btt(const float* __restrict__ mlw, bf16* __restrict__ btt){
  int c = blockIdx.x;            // 0..32767 (permuted)
  int d = threadIdx.x;           // 0..159
  int w = ((c >> 10) << 3) | (c & 7);
  int h = (c >> 3) & 127;
  float v = 0.0f;
  if (d < DD) v = mlw[(size_t)w*(HH*DD) + h*DD + d];
  int kk = d >> 5, q = (d >> 3) & 3, jj = d & 7;
  btt[(((size_t)(kk*4 + q))*NC + c)*8 + jj] = f2bf(v);
}

// ---------------- prep: pack fp32 weight matrix [K][256] -> f16 uint4 [K/8][256] ----------------
__global__ void prep_packw(const float* __restrict__ src, uint4* __restrict__ dst){
  int c = blockIdx.x, j = threadIdx.x;   // chunk of 8 rows, col
  union { _Float16 h[8]; uint4 v; } u;
  #pragma unroll
  for (int r = 0; r < 8; ++r) u.h[r] = (_Float16)src[(size_t)(c*8+r)*WW + j];
  dst[c*WW + j] = u.v;
}

// ---------------- Abias[a][b][h] = ml_b[h*136:+136] . coeff[b,a,:] (fp32) ----------------
__global__ void abias_kernel(const float* __restrict__ mlb, const float* __restrict__ logsig,
                             float* __restrict__ Abias){
  int a = blockIdx.x, b = blockIdx.y;
  int h = threadIdx.x;           // 128
  __shared__ float cf[DD];
  for (int d = h; d < DD; d += HH) cf[d] = logsig[(size_t)(b*SS + a)*LL + 1 + d];
  __syncthreads();
  float acc = 0.f;
  const float* mb = mlb + (size_t)h*DD;
  #pragma unroll 8
  for (int d = 0; d < DD; ++d) acc += cf[d] * mb[d];
  Abias[((size_t)a*BB + b)*HH + h] = acc;
}

// ---------------- A-GEMM (R6 form): 128x128 tile, MFMA 16x16x32 bf16 ----------------
// 512 thr / 8 waves, wave tile 32x64 (2x4 frags), K=160 staged ONCE (reg-staged,
// lane-linear LDS), one barrier, 320 MFMAs/block. LDS: A 40KB | B 40KB; epilogue
// aliases A region. 2 blocks/CU.
__global__ __launch_bounds__(512) void agemm_kernel(const bf16* __restrict__ cA,
                                                    const bf16* __restrict__ btt,
                                                    _Float16* __restrict__ As, int mAbs0){
  __shared__ __align__(16) char smb[81920];
  short* sm = (short*)smb;
  int mt = blockIdx.x, nt = blockIdx.y;
  int t = threadIdx.x, lane = t & 63, wid = t >> 6;
  int mBlockAbs = mAbs0 + mt*128;
  int c0 = nt*128;
  int mW = (wid & 3)*32, cW = (wid >> 2)*64;
  const uint4* aK = (const uint4*)cA;
  const uint4* bK = (const uint4*)btt;

  uint4 va[5], vb[5];
  #pragma unroll
  for (int r = 0; r < 5; ++r){
    int lin = t + r*512;         // 0..2559
    int kq = lin >> 7;           // (kk*4+q), 0..19
    int row = lin & 127;
    va[r] = aK[(size_t)kq*8192 + mBlockAbs + row];
    vb[r] = bK[(size_t)kq*NC + c0 + row];
  }
  #pragma unroll
  for (int r = 0; r < 5; ++r){
    int lin = t + r*512;
    *(uint4*)(smb + lin*16) = va[r];
    *(uint4*)(smb + 40960 + lin*16) = vb[r];
  }
  __syncthreads();

  f32x4 acc[2][4];
  #pragma unroll
  for (int i = 0; i < 2; ++i)
    #pragma unroll
    for (int j = 0; j < 4; ++j)
      acc[i][j] = (f32x4){0.f,0.f,0.f,0.f};

  const int mr = lane & 15, q = lane >> 4;
  #pragma unroll
  for (int kk = 0; kk < 5; ++kk){
    short8 af[2], bfr[4];
    #pragma unroll
    for (int mi = 0; mi < 2; ++mi)
      af[mi]  = *(const short8*)(smb + ((size_t)((kk*4+q)*128) + mW + mi*16 + mr)*16);
    #pragma unroll
    for (int ci = 0; ci < 4; ++ci)
      bfr[ci] = *(const short8*)(smb + 40960 + ((size_t)((kk*4+q)*128) + cW + ci*16 + mr)*16);
    #pragma unroll
    for (int mi = 0; mi < 2; ++mi)
      #pragma unroll
      for (int ci = 0; ci < 4; ++ci)
        acc[mi][ci] = __builtin_amdgcn_mfma_f32_16x16x32_bf16(af[mi], bfr[ci], acc[mi][ci], 0, 0, 0);
  }
  __syncthreads();   // all ds_reads done -> safe to alias sm as output buffer

  #pragma unroll
  for (int mi = 0; mi < 2; ++mi)
    #pragma unroll
    for (int ci = 0; ci < 4; ++ci){
      int col = cW + ci*16 + mr;
      #pragma unroll
      for (int r = 0; r < 4; ++r){
        int row = mW + mi*16 + q*4 + r;
        _Float16 hv = (_Float16)acc[mi][ci][r];
        sm[row*136 + col] = *(short*)&hv;
      }
    }
  __syncthreads();
  int mLocBlock = mt*128;
  #pragma unroll
  for (int rep = 0; rep < 4; ++rep){
    int idx = t + rep*512;
    int row = idx >> 4, seg = idx & 15;
    uint4 v = *(const uint4*)&sm[row*136 + seg*8];
    *(uint4*)(As + (size_t)(mLocBlock + row)*NC + c0 + seg*8) = v;
  }
}

// ---------------- scan: 1 block/batch, 512 threads (8 waves) ----------------
// MLP: j = wave*32 + (lane&31), 2-way K-split q = lane>>5, reduce via shfl_xor(32).
// A-matvec: h = wave*16 + (lane&15), 4-way W-split q4 = lane>>4, xor16+xor32 reduce
// -> full sum in every lane. 3 internal barriers per func.
__device__ __forceinline__ float nrde_func(
    int j, int q, int h, int q4,
    const uint4 (&w1r)[8], const uint4 (&w2r)[16], const uint4 (&vor)[16],
    const uint4 (&ar)[8], float ab,
    const _Float16* yh, _Float16* h1h, _Float16* h2h, _Float16* h3h,
    float b1, float b2, float bv, float inv_dtf)
{
  // L1: 128 -> 256, relu
  {
    const uint4* yp = (const uint4*)yh + (q << 3);
    float a0 = 0.f, a1 = 0.f;
    #pragma unroll
    for (int cc = 0; cc < 8; cc += 2){
      a0 = dot8(w1r[cc],   yp[cc],   a0);
      a1 = dot8(w1r[cc+1], yp[cc+1], a1);
    }
    float acc = a0 + a1;
    acc += __shfl_xor(acc, 32);
    if (q == 0){ float v = b1 + acc; h1h[j] = (_Float16)(v > 0.f ? v : 0.f); }
  }
  __syncthreads();
  // L2: 256 -> 256, relu
  {
    const uint4* hp = (const uint4*)h1h + (q << 4);
    float a0 = 0.f, a1 = 0.f, a2 = 0.f, a3 = 0.f;
    #pragma unroll
    for (int cc = 0; cc < 16; cc += 4){
      a0 = dot8(w2r[cc],   hp[cc],   a0);
      a1 = dot8(w2r[cc+1], hp[cc+1], a1);
      a2 = dot8(w2r[cc+2], hp[cc+2], a2);
      a3 = dot8(w2r[cc+3], hp[cc+3], a3);
    }
    float acc = (a0 + a1) + (a2 + a3);
    acc += __shfl_xor(acc, 32);
    if (q == 0){ float v = b2 + acc; h2h[j] = (_Float16)(v > 0.f ? v : 0.f); }
  }
  __syncthreads();
  // L3: 256 -> 256, tanh (weights in registers)
  {
    const uint4* hp = (const uint4*)h2h + (q << 4);
    float a0 = 0.f, a1 = 0.f, a2 = 0.f, a3 = 0.f;
    #pragma unroll
    for (int cc = 0; cc < 16; cc += 4){
      a0 = dot8(vor[cc],   hp[cc],   a0);
      a1 = dot8(vor[cc+1], hp[cc+1], a1);
      a2 = dot8(vor[cc+2], hp[cc+2], a2);
      a3 = dot8(vor[cc+3], hp[cc+3], a3);
    }
    float acc = (a0 + a1) + (a2 + a3);
    acc += __shfl_xor(acc, 32);
    if (q == 0) h3h[j] = (_Float16)fast_tanh(bv + acc);
  }
  __syncthreads();
  // A-matvec: k[h] = (sum_w h3[w]*A[a,b,h,w] + Abias)/dtf
  {
    const uint4* hp = (const uint4*)h3h + (q4 << 3);
    float a0 = 0.f, a1 = 0.f;
    #pragma unroll
    for (int cc = 0; cc < 8; cc += 2){
      a0 = dot8(ar[cc],   hp[cc],   a0);
      a1 = dot8(ar[cc+1], hp[cc+1], a1);
    }
    float acc = a0 + a1;
    acc += __shfl_xor(acc, 16);
    acc += __shfl_xor(acc, 32);
    return (acc + ab) * inv_dtf;   // full sum in every lane
  }
}

__global__ __launch_bounds__(512, 2) void scan_kernel(
    const float* __restrict__ times, const float* __restrict__ initial,
    const float* __restrict__ in_w, const float* __restrict__ in_b,
    const float* __restrict__ h1_b, const float* __restrict__ h2_b,
    const float* __restrict__ vo_b,
    const uint4* __restrict__ wp1, const uint4* __restrict__ wp2,
    const uint4* __restrict__ wpv,
    const _Float16* __restrict__ As, const float* __restrict__ Abias,
    float* __restrict__ y_state, float* __restrict__ out,
    int s0, int s1, int aBase)
{
  // small LDS (4.6KB): 2 blocks/CU co-reside at 124 VGPR -> 16 waves/CU TLP.
  __shared__ __align__(16) char smem[4608];
  _Float16* yh  = (_Float16*)(smem);
  _Float16* h1h = (_Float16*)(smem + 512);
  _Float16* h2h = (_Float16*)(smem + 1536);
  _Float16* h3h = (_Float16*)(smem + 2560);
  float*    yv  = (float*)(smem + 3584);

  const int b = blockIdx.x, t = threadIdx.x;
  const int wave = t >> 6, lane = t & 63;
  const int j  = (wave << 5) | (lane & 31);
  const int q  = lane >> 5;
  const int h  = (wave << 4) | (lane & 15);
  const int q4 = lane >> 4;
  const bool tail = (lane >> 4) == 0;      // 128 writer threads (h distinct)

  // loop-invariant weights + biases (compiler keeps hot subset in regs, rest L2)
  uint4 w1r[8], w2r[16], vor[16];
  #pragma unroll
  for (int cc = 0; cc < 8; ++cc)  w1r[cc] = wp1[(size_t)((q << 3) + cc)*WW + j];
  #pragma unroll
  for (int cc = 0; cc < 16; ++cc) w2r[cc] = wp2[(size_t)((q << 4) + cc)*WW + j];
  #pragma unroll
  for (int cc = 0; cc < 16; ++cc) vor[cc] = wpv[(size_t)((q << 4) + cc)*WW + j];
  const float b1 = h1_b[j], b2 = h2_b[j], bv = vo_b[j];

  if (s0 == 0){
    if (t < HH){
      float acc = in_b[t];
      for (int i = 0; i < DIN; ++i)
        acc += initial[b*DIN + i] * in_w[(size_t)i*HH + t];
      yv[t] = acc; yh[t] = (_Float16)acc;
      out[(size_t)b*(SS+1)*HH + t] = acc;
    }
  } else if (t < HH){
    float v = y_state[b*HH + t];
    yv[t] = v; yh[t] = (_Float16)v;
  }

  // preload A slice + bias for k1 of step s0 (a-index a1(s0));
  // thereafter k2's slice (index n) is reused as next step's k1 slice.
  uint4 ar[8];
  float ab;
  {
    int a1s = (s0 >= 1) ? (s0 - 1) : 0;
    const uint4* Ap = (const uint4*)(As + ((size_t)(a1s - aBase)*BB + b)*NC);
    #pragma unroll
    for (int cc = 0; cc < 8; ++cc) ar[cc] = Ap[(size_t)((q4 << 3) + cc)*HH + h];
    ab = Abias[((size_t)a1s*BB + b)*HH + h];
  }
  __syncthreads();

  for (int n = s0; n < s1; ++n){
    float dt = times[n+1] - times[n];
    int idx1 = (n >= 1) ? n : 1;               // clip(searchsorted(times, t0), 1, S)
    float inv1 = 1.f/(times[idx1] - times[idx1-1]);
    float invd = 1.f/dt;

    float k1 = nrde_func(j, q, h, q4, w1r, w2r, vor, ar, ab,
                         yh, h1h, h2h, h3h, b1, b2, bv, inv1);
    if (tail) yh[h] = (_Float16)(yv[h] + dt*k1);
    __syncthreads();

    // refresh ar/ab to a-index n (used by k2 and next step's k1);
    // loads issued here, latency covered by k2's first three segments.
    {
      const uint4* Ap = (const uint4*)(As + ((size_t)(n - aBase)*BB + b)*NC);
      #pragma unroll
      for (int cc = 0; cc < 8; ++cc) ar[cc] = Ap[(size_t)((q4 << 3) + cc)*HH + h];
      ab = Abias[((size_t)n*BB + b)*HH + h];
    }
    float k2 = nrde_func(j, q, h, q4, w1r, w2r, vor, ar, ab,
                         yh, h1h, h2h, h3h, b1, b2, bv, invd);
    if (tail){
      float ynew = yv[h] + 0.5f*dt*(k1 + k2);
      yv[h] = ynew; yh[h] = (_Float16)ynew;
      out[((size_t)b*(SS+1) + (n+1))*HH + h] = ynew;
    }
    __syncthreads();
  }

  if (tail){
    y_state[b*HH + h] = yv[h];
    if (s1 == SS) out[OUT2_OFF + (size_t)b*HH + h] = yv[h];
  }
}

extern "C" void kernel_launch(void* const* d_in, const int* in_sizes, int n_in,
                              void* d_out, int out_size, void* d_ws, size_t ws_size,
                              hipStream_t stream)
{
  (void)in_sizes; (void)n_in; (void)out_size;
  const float* times   = (const float*)d_in[0];
  const float* logsig  = (const float*)d_in[1];
  const float* initial = (const float*)d_in[2];
  const float* in_w    = (const float*)d_in[3];
  const float* in_b    = (const float*)d_in[4];
  const float* h1_w    = (const float*)d_in[5];
  const float* h1_b    = (const float*)d_in[6];
  const float* h2_w    = (const float*)d_in[7];
  const float* h2_b    = (const float*)d_in[8];
  const float* vo_w    = (const float*)d_in[9];
  const float* vo_b    = (const float*)d_in[10];
  const float* ml_w    = (const float*)d_in[11];
  const float* ml_b    = (const float*)d_in[12];
  float* out = (float*)d_out;

  char* ws = (char*)d_ws;
  size_t off = 0;
  bf16* cA      = (bf16*)(ws + off); off += (size_t)8192*KP*2;        // 2.62 MB (K-blocked)
  bf16* btt     = (bf16*)(ws + off); off += (size_t)NC*KP*2;          // 10.49 MB (K-blocked)
  float* Abias  = (float*)(ws + off); off += (size_t)SS*BB*HH*4;      // 4.19 MB
  float* y_state= (float*)(ws + off); off += (size_t)BB*HH*4;         // 64 KB
  uint4* wp1    = (uint4*)(ws + off); off += (size_t)16*WW*16;        // 64 KB
  uint4* wp2    = (uint4*)(ws + off); off += (size_t)32*WW*16;        // 128 KB
  uint4* wpv    = (uint4*)(ws + off); off += (size_t)32*WW*16;        // 128 KB
  _Float16* As  = (_Float16*)(ws + off);
  size_t perA = (size_t)BB*HH*WW*2;                                   // 8.39 MB per a-index
  size_t avail = (ws_size > off) ? (ws_size - off) : 0;
  int C = (int)(avail / perA);
  if (C > SS) C = SS;
  if (C < 2) return;  // workspace too small -> fail loudly

  prep_coeff<<<8192, 160, 0, stream>>>(logsig, cA);
  prep_btt<<<NC, 160, 0, stream>>>(ml_w, btt);
  abias_kernel<<<dim3(SS, BB), HH, 0, stream>>>(ml_b, logsig, Abias);
  prep_packw<<<16, WW, 0, stream>>>(h1_w, wp1);
  prep_packw<<<32, WW, 0, stream>>>(h2_w, wp2);
  prep_packw<<<32, WW, 0, stream>>>(vo_w, wpv);

  // Chunked over A-indices; consecutive chunks overlap by 1 (step n needs A[n-1], A[n]).
  int s = 0, aB = 0;
  while (s < SS){
    int cc = SS - aB; if (cc > C) cc = C;
    agemm_kernel<<<dim3(cc, 256), 512, 0, stream>>>(cA, btt, As, aB*128);
    int sEnd = aB + cc; if (sEnd > SS) sEnd = SS;
    scan_kernel<<<BB, 512, 0, stream>>>(times, initial, in_w, in_b,
        h1_b, h2_b, vo_b, wp1, wp2, wpv, As, Abias, y_state, out, s, sEnd, aB);
    s = sEnd;
    aB = sEnd - 1;
  }
}

// Round 14
// 604.959 us; speedup vs baseline: 1.0080x; 1.0080x over previous
//
#include <hip/hip_runtime.h>
#include <hip/hip_bf16.h>

// NRDE layer. Structure:
//   A[a][b][.] = coeff[b,a,:] @ btt^T   (bf16 MFMA GEMM, fp32 accum, stored f16)
//     A column order is permuted: c' = (w>>3)*1024 + h*8 + (w&7), so the scan's
//     A-matvec reads contiguous 128B granules per 8-lane group.
//   GEMM operands pre-stored K-BLOCKED: [kk*4+q][row][8 bf16] -> lane-linear
//   staging, conflict-free ds_read_b128 fragments, zero padding.
//   agemm: R6 form (best measured): grid (cc,256), 512 thr / 8 waves, wave tile
//     32x64, full K staged once, ONE barrier, 320 MFMAs/block, 80KB LDS.
//   scan: 1 block of 512 thr (8 waves) per batch element.
//     amdgpu_waves_per_eu(2,2) FORCES the allocator budget to 256 VGPR/wave so
//     all loop-invariant weights (w1:32 + w2:64 + vo:64 VGPRs) stay RESIDENT
//     across the 64-step loop (R11/R12 showed the default heuristic caps at 124
//     and rematerializes ~2.1GB of L2 weight loads onto the critical path).
//     Grid is 128 blocks on 256 CUs -> occupancy is structural; latency is king.
//     A-slice for k2 (index n) is REUSED as next step's k1 slice (a1(n+1)=n).
// (Resubmission of the R13 candidate: R13 never ran — container-level infra
//  failure, same signature as R5/R9 whose verbatim resubmissions passed.)

#define BB 128
#define SS 64
#define LL 137
#define HH 128
#define DIN 64
#define WW 256
#define DD 136          // L-1
#define KP 160          // GEMM K padded to 5*32
#define NC 32768        // H*W
#define OUT2_OFF ((size_t)BB*(SS+1)*HH)

typedef __hip_bfloat16 bf16;
typedef __attribute__((ext_vector_type(8))) short short8;
typedef __attribute__((ext_vector_type(4))) float f32x4;
typedef _Float16 h2t __attribute__((ext_vector_type(2)));

__device__ __forceinline__ bf16 f2bf(float x){ return __float2bfloat16(x); }

__device__ __forceinline__ float fdot2u(unsigned w, unsigned y, float acc){
#if __has_builtin(__builtin_amdgcn_fdot2)
  return __builtin_amdgcn_fdot2(__builtin_bit_cast(h2t, w),
                                __builtin_bit_cast(h2t, y), acc, false);
#else
  h2t a = __builtin_bit_cast(h2t, w), b2 = __builtin_bit_cast(h2t, y);
  return acc + (float)a[0]*(float)b2[0] + (float)a[1]*(float)b2[1];
#endif
}
__device__ __forceinline__ float dot8(uint4 w, uint4 y, float acc){
  acc = fdot2u(w.x, y.x, acc);
  acc = fdot2u(w.y, y.y, acc);
  acc = fdot2u(w.z, y.z, acc);
  acc = fdot2u(w.w, y.w, acc);
  return acc;
}

__device__ __forceinline__ float fast_tanh(float x){
  float e = __expf(2.f*x);
#if __has_builtin(__builtin_amdgcn_rcpf)
  float r = __builtin_amdgcn_rcpf(e + 1.f);
#else
  float r = 1.f/(e + 1.f);
#endif
  return 1.f - 2.f*r;
}

// ---------------- prep: coeff rows m=a*128+b (fp32 -> bf16), K-BLOCKED ----------------
__global__ void prep_coeff(const float* __restrict__ logsig, bf16* __restrict__ cA){
  int m = blockIdx.x;            // 0..8191
  int d = threadIdx.x;           // 0..159
  int a = m >> 7, b = m & 127;
  float v = 0.0f;
  if (d < DD) v = logsig[(size_t)(b*SS + a)*LL + 1 + d];
  int kk = d >> 5, q = (d >> 3) & 3, jj = d & 7;
  cA[(((size_t)(kk*4 + q))*8192 + m)*8 + jj] = f2bf(v);
}

// ---------------- prep: btt rows in PERMUTED col order c', K-BLOCKED ----------------
// c' = wc*1024 + h*8 + wlow -> w = ((c'>>10)<<3)|(c'&7), h = (c'>>3)&127
__global__ void prep_btt(const float* __restrict__ mlw, bf16* __restrict__ btt){
  int c = blockIdx.x;            // 0..32767 (permuted)
  int d = threadIdx.x;           // 0..159
  int w = ((c >> 10) << 3) | (c & 7);
  int h = (c >> 3) & 127;
  float v = 0.0f;
  if (d < DD) v = mlw[(size_t)w*(HH*DD) + h*DD + d];
  int kk = d >> 5, q = (d >> 3) & 3, jj = d & 7;
  btt[(((size_t)(kk*4 + q))*NC + c)*8 + jj] = f2bf(v);
}

// ---------------- prep: pack fp32 weight matrix [K][256] -> f16 uint4 [K/8][256] ----------------
__global__ void prep_packw(const float* __restrict__ src, uint4* __restrict__ dst){
  int c = blockIdx.x, j = threadIdx.x;   // chunk of 8 rows, col
  union { _Float16 h[8]; uint4 v; } u;
  #pragma unroll
  for (int r = 0; r < 8; ++r) u.h[r] = (_Float16)src[(size_t)(c*8+r)*WW + j];
  dst[c*WW + j] = u.v;
}

// ---------------- Abias[a][b][h] = ml_b[h*136:+136] . coeff[b,a,:] (fp32) ----------------
__global__ void abias_kernel(const float* __restrict__ mlb, const float* __restrict__ logsig,
                             float* __restrict__ Abias){
  int a = blockIdx.x, b = blockIdx.y;
  int h = threadIdx.x;           // 128
  __shared__ float cf[DD];
  for (int d = h; d < DD; d += HH) cf[d] = logsig[(size_t)(b*SS + a)*LL + 1 + d];
  __syncthreads();
  float acc = 0.f;
  const float* mb = mlb + (size_t)h*DD;
  #pragma unroll 8
  for (int d = 0; d < DD; ++d) acc += cf[d] * mb[d];
  Abias[((size_t)a*BB + b)*HH + h] = acc;
}

// ---------------- A-GEMM (R6 form): 128x128 tile, MFMA 16x16x32 bf16 ----------------
// 512 thr / 8 waves, wave tile 32x64 (2x4 frags), K=160 staged ONCE (reg-staged,
// lane-linear LDS), one barrier, 320 MFMAs/block. LDS: A 40KB | B 40KB; epilogue
// aliases A region. 2 blocks/CU.
__global__ __launch_bounds__(512) void agemm_kernel(const bf16* __restrict__ cA,
                                                    const bf16* __restrict__ btt,
                                                    _Float16* __restrict__ As, int mAbs0){
  __shared__ __align__(16) char smb[81920];
  short* sm = (short*)smb;
  int mt = blockIdx.x, nt = blockIdx.y;
  int t = threadIdx.x, lane = t & 63, wid = t >> 6;
  int mBlockAbs = mAbs0 + mt*128;
  int c0 = nt*128;
  int mW = (wid & 3)*32, cW = (wid >> 2)*64;
  const uint4* aK = (const uint4*)cA;
  const uint4* bK = (const uint4*)btt;

  uint4 va[5], vb[5];
  #pragma unroll
  for (int r = 0; r < 5; ++r){
    int lin = t + r*512;         // 0..2559
    int kq = lin >> 7;           // (kk*4+q), 0..19
    int row = lin & 127;
    va[r] = aK[(size_t)kq*8192 + mBlockAbs + row];
    vb[r] = bK[(size_t)kq*NC + c0 + row];
  }
  #pragma unroll
  for (int r = 0; r < 5; ++r){
    int lin = t + r*512;
    *(uint4*)(smb + lin*16) = va[r];
    *(uint4*)(smb + 40960 + lin*16) = vb[r];
  }
  __syncthreads();

  f32x4 acc[2][4];
  #pragma unroll
  for (int i = 0; i < 2; ++i)
    #pragma unroll
    for (int j = 0; j < 4; ++j)
      acc[i][j] = (f32x4){0.f,0.f,0.f,0.f};

  const int mr = lane & 15, q = lane >> 4;
  #pragma unroll
  for (int kk = 0; kk < 5; ++kk){
    short8 af[2], bfr[4];
    #pragma unroll
    for (int mi = 0; mi < 2; ++mi)
      af[mi]  = *(const short8*)(smb + ((size_t)((kk*4+q)*128) + mW + mi*16 + mr)*16);
    #pragma unroll
    for (int ci = 0; ci < 4; ++ci)
      bfr[ci] = *(const short8*)(smb + 40960 + ((size_t)((kk*4+q)*128) + cW + ci*16 + mr)*16);
    #pragma unroll
    for (int mi = 0; mi < 2; ++mi)
      #pragma unroll
      for (int ci = 0; ci < 4; ++ci)
        acc[mi][ci] = __builtin_amdgcn_mfma_f32_16x16x32_bf16(af[mi], bfr[ci], acc[mi][ci], 0, 0, 0);
  }
  __syncthreads();   // all ds_reads done -> safe to alias sm as output buffer

  #pragma unroll
  for (int mi = 0; mi < 2; ++mi)
    #pragma unroll
    for (int ci = 0; ci < 4; ++ci){
      int col = cW + ci*16 + mr;
      #pragma unroll
      for (int r = 0; r < 4; ++r){
        int row = mW + mi*16 + q*4 + r;
        _Float16 hv = (_Float16)acc[mi][ci][r];
        sm[row*136 + col] = *(short*)&hv;
      }
    }
  __syncthreads();
  int mLocBlock = mt*128;
  #pragma unroll
  for (int rep = 0; rep < 4; ++rep){
    int idx = t + rep*512;
    int row = idx >> 4, seg = idx & 15;
    uint4 v = *(const uint4*)&sm[row*136 + seg*8];
    *(uint4*)(As + (size_t)(mLocBlock + row)*NC + c0 + seg*8) = v;
  }
}

// ---------------- scan: 1 block/batch, 512 threads (8 waves) ----------------
// MLP: j = wave*32 + (lane&31), 2-way K-split q = lane>>5, reduce via shfl_xor(32).
// A-matvec: h = wave*16 + (lane&15), 4-way W-split q4 = lane>>4, xor16+xor32 reduce
// -> full sum in every lane. 3 internal barriers per func.
__device__ __forceinline__ float nrde_func(
    int j, int q, int h, int q4,
    const uint4 (&w1r)[8], const uint4 (&w2r)[16], const uint4 (&vor)[16],
    const uint4 (&ar)[8], float ab,
    const _Float16* yh, _Float16* h1h, _Float16* h2h, _Float16* h3h,
    float b1, float b2, float bv, float inv_dtf)
{
  // L1: 128 -> 256, relu
  {
    const uint4* yp = (const uint4*)yh + (q << 3);
    float a0 = 0.f, a1 = 0.f;
    #pragma unroll
    for (int cc = 0; cc < 8; cc += 2){
      a0 = dot8(w1r[cc],   yp[cc],   a0);
      a1 = dot8(w1r[cc+1], yp[cc+1], a1);
    }
    float acc = a0 + a1;
    acc += __shfl_xor(acc, 32);
    if (q == 0){ float v = b1 + acc; h1h[j] = (_Float16)(v > 0.f ? v : 0.f); }
  }
  __syncthreads();
  // L2: 256 -> 256, relu
  {
    const uint4* hp = (const uint4*)h1h + (q << 4);
    float a0 = 0.f, a1 = 0.f, a2 = 0.f, a3 = 0.f;
    #pragma unroll
    for (int cc = 0; cc < 16; cc += 4){
      a0 = dot8(w2r[cc],   hp[cc],   a0);
      a1 = dot8(w2r[cc+1], hp[cc+1], a1);
      a2 = dot8(w2r[cc+2], hp[cc+2], a2);
      a3 = dot8(w2r[cc+3], hp[cc+3], a3);
    }
    float acc = (a0 + a1) + (a2 + a3);
    acc += __shfl_xor(acc, 32);
    if (q == 0){ float v = b2 + acc; h2h[j] = (_Float16)(v > 0.f ? v : 0.f); }
  }
  __syncthreads();
  // L3: 256 -> 256, tanh (weights in registers)
  {
    const uint4* hp = (const uint4*)h2h + (q << 4);
    float a0 = 0.f, a1 = 0.f, a2 = 0.f, a3 = 0.f;
    #pragma unroll
    for (int cc = 0; cc < 16; cc += 4){
      a0 = dot8(vor[cc],   hp[cc],   a0);
      a1 = dot8(vor[cc+1], hp[cc+1], a1);
      a2 = dot8(vor[cc+2], hp[cc+2], a2);
      a3 = dot8(vor[cc+3], hp[cc+3], a3);
    }
    float acc = (a0 + a1) + (a2 + a3);
    acc += __shfl_xor(acc, 32);
    if (q == 0) h3h[j] = (_Float16)fast_tanh(bv + acc);
  }
  __syncthreads();
  // A-matvec: k[h] = (sum_w h3[w]*A[a,b,h,w] + Abias)/dtf
  {
    const uint4* hp = (const uint4*)h3h + (q4 << 3);
    float a0 = 0.f, a1 = 0.f;
    #pragma unroll
    for (int cc = 0; cc < 8; cc += 2){
      a0 = dot8(ar[cc],   hp[cc],   a0);
      a1 = dot8(ar[cc+1], hp[cc+1], a1);
    }
    float acc = a0 + a1;
    acc += __shfl_xor(acc, 16);
    acc += __shfl_xor(acc, 32);
    return (acc + ab) * inv_dtf;   // full sum in every lane
  }
}

__global__ __launch_bounds__(512, 2)
__attribute__((amdgpu_waves_per_eu(2, 2)))
void scan_kernel(
    const float* __restrict__ times, const float* __restrict__ initial,
    const float* __restrict__ in_w, const float* __restrict__ in_b,
    const float* __restrict__ h1_b, const float* __restrict__ h2_b,
    const float* __restrict__ vo_b,
    const uint4* __restrict__ wp1, const uint4* __restrict__ wp2,
    const uint4* __restrict__ wpv,
    const _Float16* __restrict__ As, const float* __restrict__ Abias,
    float* __restrict__ y_state, float* __restrict__ out,
    int s0, int s1, int aBase)
{
  __shared__ __align__(16) char smem[4608];
  _Float16* yh  = (_Float16*)(smem);
  _Float16* h1h = (_Float16*)(smem + 512);
  _Float16* h2h = (_Float16*)(smem + 1536);
  _Float16* h3h = (_Float16*)(smem + 2560);
  float*    yv  = (float*)(smem + 3584);

  const int b = blockIdx.x, t = threadIdx.x;
  const int wave = t >> 6, lane = t & 63;
  const int j  = (wave << 5) | (lane & 31);
  const int q  = lane >> 5;
  const int h  = (wave << 4) | (lane & 15);
  const int q4 = lane >> 4;
  const bool tail = (lane >> 4) == 0;      // 128 writer threads (h distinct)

  // loop-invariant weights + biases: with waves_per_eu(2,2) the allocator has a
  // 256-VGPR budget -> these stay RESIDENT across the whole 64-step loop.
  uint4 w1r[8], w2r[16], vor[16];
  #pragma unroll
  for (int cc = 0; cc < 8; ++cc)  w1r[cc] = wp1[(size_t)((q << 3) + cc)*WW + j];
  #pragma unroll
  for (int cc = 0; cc < 16; ++cc) w2r[cc] = wp2[(size_t)((q << 4) + cc)*WW + j];
  #pragma unroll
  for (int cc = 0; cc < 16; ++cc) vor[cc] = wpv[(size_t)((q << 4) + cc)*WW + j];
  const float b1 = h1_b[j], b2 = h2_b[j], bv = vo_b[j];

  if (s0 == 0){
    if (t < HH){
      float acc = in_b[t];
      for (int i = 0; i < DIN; ++i)
        acc += initial[b*DIN + i] * in_w[(size_t)i*HH + t];
      yv[t] = acc; yh[t] = (_Float16)acc;
      out[(size_t)b*(SS+1)*HH + t] = acc;
    }
  } else if (t < HH){
    float v = y_state[b*HH + t];
    yv[t] = v; yh[t] = (_Float16)v;
  }

  // preload A slice + bias for k1 of step s0 (a-index a1(s0));
  // thereafter k2's slice (index n) is reused as next step's k1 slice.
  uint4 ar[8];
  float ab;
  {
    int a1s = (s0 >= 1) ? (s0 - 1) : 0;
    const uint4* Ap = (const uint4*)(As + ((size_t)(a1s - aBase)*BB + b)*NC);
    #pragma unroll
    for (int cc = 0; cc < 8; ++cc) ar[cc] = Ap[(size_t)((q4 << 3) + cc)*HH + h];
    ab = Abias[((size_t)a1s*BB + b)*HH + h];
  }
  __syncthreads();

  for (int n = s0; n < s1; ++n){
    float dt = times[n+1] - times[n];
    int idx1 = (n >= 1) ? n : 1;               // clip(searchsorted(times, t0), 1, S)
    float inv1 = 1.f/(times[idx1] - times[idx1-1]);
    float invd = 1.f/dt;

    float k1 = nrde_func(j, q, h, q4, w1r, w2r, vor, ar, ab,
                         yh, h1h, h2h, h3h, b1, b2, bv, inv1);
    if (tail) yh[h] = (_Float16)(yv[h] + dt*k1);
    __syncthreads();

    // refresh ar/ab to a-index n (used by k2 and next step's k1);
    // loads issued here, latency covered by k2's first three segments.
    {
      const uint4* Ap = (const uint4*)(As + ((size_t)(n - aBase)*BB + b)*NC);
      #pragma unroll
      for (int cc = 0; cc < 8; ++cc) ar[cc] = Ap[(size_t)((q4 << 3) + cc)*HH + h];
      ab = Abias[((size_t)n*BB + b)*HH + h];
    }
    float k2 = nrde_func(j, q, h, q4, w1r, w2r, vor, ar, ab,
                         yh, h1h, h2h, h3h, b1, b2, bv, invd);
    if (tail){
      float ynew = yv[h] + 0.5f*dt*(k1 + k2);
      yv[h] = ynew; yh[h] = (_Float16)ynew;
      out[((size_t)b*(SS+1) + (n+1))*HH + h] = ynew;
    }
    __syncthreads();
  }

  if (tail){
    y_state[b*HH + h] = yv[h];
    if (s1 == SS) out[OUT2_OFF + (size_t)b*HH + h] = yv[h];
  }
}

extern "C" void kernel_launch(void* const* d_in, const int* in_sizes, int n_in,
                              void* d_out, int out_size, void* d_ws, size_t ws_size,
                              hipStream_t stream)
{
  (void)in_sizes; (void)n_in; (void)out_size;
  const float* times   = (const float*)d_in[0];
  const float* logsig  = (const float*)d_in[1];
  const float* initial = (const float*)d_in[2];
  const float* in_w    = (const float*)d_in[3];
  const float* in_b    = (const float*)d_in[4];
  const float* h1_w    = (const float*)d_in[5];
  const float* h1_b    = (const float*)d_in[6];
  const float* h2_w    = (const float*)d_in[7];
  const float* h2_b    = (const float*)d_in[8];
  const float* vo_w    = (const float*)d_in[9];
  const float* vo_b    = (const float*)d_in[10];
  const float* ml_w    = (const float*)d_in[11];
  const float* ml_b    = (const float*)d_in[12];
  float* out = (float*)d_out;

  char* ws = (char*)d_ws;
  size_t off = 0;
  bf16* cA      = (bf16*)(ws + off); off += (size_t)8192*KP*2;        // 2.62 MB (K-blocked)
  bf16* btt     = (bf16*)(ws + off); off += (size_t)NC*KP*2;          // 10.49 MB (K-blocked)
  float* Abias  = (float*)(ws + off); off += (size_t)SS*BB*HH*4;      // 4.19 MB
  float* y_state= (float*)(ws + off); off += (size_t)BB*HH*4;         // 64 KB
  uint4* wp1    = (uint4*)(ws + off); off += (size_t)16*WW*16;        // 64 KB
  uint4* wp2    = (uint4*)(ws + off); off += (size_t)32*WW*16;        // 128 KB
  uint4* wpv    = (uint4*)(ws + off); off += (size_t)32*WW*16;        // 128 KB
  _Float16* As  = (_Float16*)(ws + off);
  size_t perA = (size_t)BB*HH*WW*2;                                   // 8.39 MB per a-index
  size_t avail = (ws_size > off) ? (ws_size - off) : 0;
  int C = (int)(avail / perA);
  if (C > SS) C = SS;
  if (C < 2) return;  // workspace too small -> fail loudly

  prep_coeff<<<8192, 160, 0, stream>>>(logsig, cA);
  prep_btt<<<NC, 160, 0, stream>>>(ml_w, btt);
  abias_kernel<<<dim3(SS, BB), HH, 0, stream>>>(ml_b, logsig, Abias);
  prep_packw<<<16, WW, 0, stream>>>(h1_w, wp1);
  prep_packw<<<32, WW, 0, stream>>>(h2_w, wp2);
  prep_packw<<<32, WW, 0, stream>>>(vo_w, wpv);

  // Chunked over A-indices; consecutive chunks overlap by 1 (step n needs A[n-1], A[n]).
  int s = 0, aB = 0;
  while (s < SS){
    int cc = SS - aB; if (cc > C) cc = C;
    agemm_kernel<<<dim3(cc, 256), 512, 0, stream>>>(cA, btt, As, aB*128);
    int sEnd = aB + cc; if (sEnd > SS) sEnd = SS;
    scan_kernel<<<BB, 512, 0, stream>>>(times, initial, in_w, in_b,
        h1_b, h2_b, vo_b, wp1, wp2, wpv, As, Abias, y_state, out, s, sEnd, aB);
    s = sEnd;
    aB = sEnd - 1;
  }
}